// Round 1
// baseline (518.097 us; speedup 1.0000x reference)
//
#include <hip/hip_runtime.h>
#include <math.h>

#define EMB_D 768
#define SEQ_S 512
#define BLOCK 1024
#define NWAVES (BLOCK / 64)          // 16 waves
#define ROWS_PER_WAVE (SEQ_S / NWAVES) // 32 rows per wave

// One block per batch element. Phase 1: each wave computes, for its rows s,
// score[s] = emb[b,s,:]·w_att and t[s] = emb[b,s,:]·w_pred in a single pass
// over the row (single HBM read of embeddings — the only O(B*S*D) traffic).
// Phase 2: block-wide softmax over score[0..511] and weighted sum of t,
// then sigmoid(sum + b_pred) -> out[b].
__global__ __launch_bounds__(BLOCK, 1) void attn_pool_kernel(
    const float* __restrict__ emb,     // [B, S, D]
    const float* __restrict__ w_att,   // [D]
    const float* __restrict__ w_pred,  // [D]
    const float* __restrict__ b_pred,  // [1]
    float* __restrict__ out)           // [B]
{
    __shared__ float s_score[SEQ_S];
    __shared__ float s_t[SEQ_S];
    __shared__ float s_red_a[NWAVES];
    __shared__ float s_red_b[NWAVES];

    const int b    = blockIdx.x;
    const int tid  = threadIdx.x;
    const int lane = tid & 63;
    const int wave = tid >> 6;

    // Weight fragments in registers: lane covers float4 indices lane, lane+64, lane+128
    const float4* wa4 = (const float4*)w_att;
    const float4* wp4 = (const float4*)w_pred;
    float4 wa[3], wp[3];
#pragma unroll
    for (int c = 0; c < 3; ++c) {
        wa[c] = wa4[lane + 64 * c];
        wp[c] = wp4[lane + 64 * c];
    }

    const float4* e4 = (const float4*)(emb + (size_t)b * SEQ_S * EMB_D);

    // ---- Phase 1: per-row dual dot products ----
#pragma unroll 1
    for (int r = 0; r < ROWS_PER_WAVE; ++r) {
        const int s = wave * ROWS_PER_WAVE + r;
        const float4* row = e4 + (size_t)s * (EMB_D / 4);
        float sa = 0.f, sp = 0.f;
#pragma unroll
        for (int c = 0; c < 3; ++c) {
            float4 v = row[lane + 64 * c];
            sa = fmaf(v.x, wa[c].x, sa);
            sa = fmaf(v.y, wa[c].y, sa);
            sa = fmaf(v.z, wa[c].z, sa);
            sa = fmaf(v.w, wa[c].w, sa);
            sp = fmaf(v.x, wp[c].x, sp);
            sp = fmaf(v.y, wp[c].y, sp);
            sp = fmaf(v.z, wp[c].z, sp);
            sp = fmaf(v.w, wp[c].w, sp);
        }
        // 64-lane reduction
#pragma unroll
        for (int off = 32; off > 0; off >>= 1) {
            sa += __shfl_down(sa, off, 64);
            sp += __shfl_down(sp, off, 64);
        }
        if (lane == 0) {
            s_score[s] = sa;
            s_t[s]     = sp;
        }
    }
    __syncthreads();

    // ---- Phase 2: softmax + weighted sum ----
    float score = -INFINITY, tval = 0.f;
    if (tid < SEQ_S) {
        score = s_score[tid];
        tval  = s_t[tid];
    }

    // block max
    float m = score;
#pragma unroll
    for (int off = 1; off < 64; off <<= 1)
        m = fmaxf(m, __shfl_xor(m, off, 64));
    if (lane == 0) s_red_a[wave] = m;
    __syncthreads();
    if (tid == 0) {
        float mm = s_red_a[0];
#pragma unroll
        for (int w = 1; w < NWAVES; ++w) mm = fmaxf(mm, s_red_a[w]);
        s_red_a[0] = mm;
    }
    __syncthreads();
    m = s_red_a[0];
    __syncthreads();   // protect s_red_a before reuse

    float e = (tid < SEQ_S) ? __expf(score - m) : 0.f;
    float se  = e;
    float set = e * tval;
#pragma unroll
    for (int off = 1; off < 64; off <<= 1) {
        se  += __shfl_xor(se, off, 64);
        set += __shfl_xor(set, off, 64);
    }
    if (lane == 0) {
        s_red_a[wave] = se;
        s_red_b[wave] = set;
    }
    __syncthreads();
    if (tid == 0) {
        float Z = 0.f, ET = 0.f;
#pragma unroll
        for (int w = 0; w < NWAVES; ++w) {
            Z  += s_red_a[w];
            ET += s_red_b[w];
        }
        float logit = ET / Z + b_pred[0];
        out[b] = 1.0f / (1.0f + __expf(-logit));
    }
}

extern "C" void kernel_launch(void* const* d_in, const int* in_sizes, int n_in,
                              void* d_out, int out_size, void* d_ws, size_t ws_size,
                              hipStream_t stream) {
    const float* emb    = (const float*)d_in[0]; // [256,512,768]
    const float* w_att  = (const float*)d_in[1]; // [768]
    const float* w_pred = (const float*)d_in[2]; // [768]
    const float* b_pred = (const float*)d_in[3]; // [1]
    float* out = (float*)d_out;                  // [256]

    const int B = in_sizes[0] / (SEQ_S * EMB_D); // 256
    attn_pool_kernel<<<B, BLOCK, 0, stream>>>(emb, w_att, w_pred, b_pred, out);
}